// Round 7
// baseline (474.458 us; speedup 1.0000x reference)
//
#include <hip/hip_runtime.h>
#include <hip/hip_bf16.h>

namespace {
constexpr int kN    = 8192;
constexpr int kFin  = 512;
constexpr int kFout = 64;
constexpr float kAlpha = 0.2f;
constexpr int kJSplit = 4;                  // j-range split for k_attn
constexpr int kJLen   = kN / kJSplit;       // 2048
constexpr int kChunks = kJLen / 128;        // 16

using bf16x8 = __attribute__((ext_vector_type(8))) short;
using f32x4  = __attribute__((ext_vector_type(4))) float;

__device__ __forceinline__ unsigned short f2bf(float x) {
  return __builtin_bit_cast(unsigned short, __float2bfloat16(x));
}
__device__ __forceinline__ float lrelu(float x) {
  return fmaxf(x, kAlpha * x);   // valid since 0<alpha<1
}
// monotone float<->uint order-preserving map (for atomicMax on float)
__device__ __forceinline__ unsigned int fkey(float x) {
  unsigned int b = __float_as_uint(x);
  return (b & 0x80000000u) ? ~b : (b | 0x80000000u);
}
__device__ __forceinline__ float fdec(unsigned int k) {
  return (k & 0x80000000u) ? __uint_as_float(k ^ 0x80000000u) : __uint_as_float(~k);
}
} // namespace

// ---------------------------------------------------------------------------
// k_prep: fused (a) linear part (blocks 0..511) and (b) adj->bitmask part
// (blocks 512..2559). Linear blocks dispatch first so their ~10 us hides
// inside the 45-us sequential adj stream.
//
// (a) h = X@W fp32; s_src/s_dst (+ global s_dst max via atomicMax); h emitted
//     as hTf in MFMA-B-fragment order (layout proven r5/r6). X rows read
//     wave-uniform from global (readfirstlane'd row base -> scalarizable);
//     W read directly (no transpose needed).
// (b) one WAVE per adj row: lane reads adj[row][it*64+lane] (256B coalesced,
//     row fully sequential => DRAM row-hit friendly); __ballot(v>0) gives the
//     64-bit mask word for 64 consecutive j (bit i = j offset i). mask is
//     8 MB = L2/L3-resident for k_attn.
// ---------------------------------------------------------------------------
__global__ __launch_bounds__(256) void k_prep(
    const int* __restrict__ adj, const float* __restrict__ X,
    const float* __restrict__ W, const float* __restrict__ A,
    unsigned long long* __restrict__ mask, unsigned short* __restrict__ hTf,
    float* __restrict__ s_src, float* __restrict__ s_dst,
    unsigned int* __restrict__ Smax_u)
{
  const int t = threadIdx.x;
  const int wv = t >> 6, lane = t & 63;

  if (blockIdx.x >= 512) {
    // ---------------- bitmask part: wave -> one adj row ----------------
    const int row = (blockIdx.x - 512) * 4 + wv;
    const int* __restrict__ ar = adj + (size_t)row * kN;
    unsigned long long* __restrict__ mr = mask + (size_t)row * 128;
#pragma unroll 8
    for (int it = 0; it < 128; ++it) {
      const int v = ar[it * 64 + lane];
      const unsigned long long bal = __ballot(v > 0);
      if (lane == (it & 63)) mr[it] = bal;
    }
    return;
  }

  // ---------------- linear part ----------------
  const int wvu = __builtin_amdgcn_readfirstlane(wv);   // provably uniform
  const int f = lane;
  const int i0 = blockIdx.x * 16;
  const int r0l = wvu * 4;

  __shared__ unsigned short h_sm[16][64];
  __shared__ float red[4];

  const float* x0 = X + (size_t)(i0 + r0l) * kFin;      // wave-uniform base
  float acc0 = 0.f, acc1 = 0.f, acc2 = 0.f, acc3 = 0.f;
#pragma unroll 2
  for (int k = 0; k < kFin; k += 4) {
    const float4 xa = *(const float4*)(x0 + k);
    const float4 xb = *(const float4*)(x0 + kFin + k);
    const float4 xc = *(const float4*)(x0 + 2 * kFin + k);
    const float4 xd = *(const float4*)(x0 + 3 * kFin + k);
#pragma unroll
    for (int j = 0; j < 4; ++j) {
      const float wk = W[(k + j) * kFout + f];          // 256B coalesced, L2
      acc0 = fmaf(((const float*)&xa)[j], wk, acc0);
      acc1 = fmaf(((const float*)&xb)[j], wk, acc1);
      acc2 = fmaf(((const float*)&xc)[j], wk, acc2);
      acc3 = fmaf(((const float*)&xd)[j], wk, acc3);
    }
  }

  // ---- scores + per-wave s_dst max ----
  const float asrc = A[f], adst = A[kFout + f];
  float accs[4] = {acc0, acc1, acc2, acc3};
  float dmax = -3.4e38f;
#pragma unroll
  for (int r = 0; r < 4; ++r) {
    float vs = accs[r] * asrc;
    float vd = accs[r] * adst;
#pragma unroll
    for (int off = 32; off > 0; off >>= 1) {
      vs += __shfl_xor(vs, off, 64);
      vd += __shfl_xor(vd, off, 64);
    }
    if (f == 0) {
      s_src[i0 + r0l + r] = vs;
      s_dst[i0 + r0l + r] = vd;
      dmax = fmaxf(dmax, vd);
    }
    h_sm[r0l + r][f] = f2bf(accs[r]);
  }
  if (f == 0) red[wvu] = dmax;
  __syncthreads();
  if (t == 0) {
    float m = fmaxf(fmaxf(red[0], red[1]), fmaxf(red[2], red[3]));
    atomicMax(Smax_u, fkey(m));
  }

  // ---- emit 2 KB hTf fragment slice, coalesced (layout proven r5/r6) ----
  if (t < 128) {
    const int jblk = i0 >> 5, half = (i0 >> 4) & 1;
    const int w = t >> 5, li = t & 31;
    const int ln = half * 32 + li;
    const int ql = li >> 4, fcol = w * 16 + (li & 15);
    bf16x8 v;
#pragma unroll
    for (int e = 0; e < 8; ++e) v[e] = (short)h_sm[ql * 8 + e][fcol];
    *(bf16x8*)(hTf + (size_t)jblk * 2048 + w * 512 + (size_t)ln * 8) = v;
  }
}

// ---------------------------------------------------------------------------
// k_attn v7: consumes the 8-MB bitmask (L2/L3-resident) instead of the raw
// 268-MB adj stream — removes the DRAM-row-thrash bottleneck. Barrier-free
// main loop (v6 structure): wave wv owns j-slice [c*128+wv*32,+32) per chunk,
// builds the MFMA A-fragment in registers, 4 MFMAs/chunk. Mask words
// prefetched one 4-chunk group ahead (named regs only — r5 scratch lesson).
// ---------------------------------------------------------------------------
__global__ __launch_bounds__(256) void k_attn(
    const unsigned long long* __restrict__ mask,
    const unsigned short* __restrict__ hTf,
    const float* __restrict__ s_src, const float* __restrict__ s_dst,
    const unsigned int* __restrict__ Smax_u, float* __restrict__ accp,
    float* __restrict__ lp)
{
  const int t = threadIdx.x;
  const int wv = t >> 6, lane = t & 63;
  const int b = blockIdx.x;
  const int i0 = (b >> 2) * 16;
  const int q = b & 3;
  const int jbase = q * kJLen;
  const int mrow = lane & 15, quad = lane >> 4;

  __shared__ float Racc[4][16][64];   // 16 KB: per-wave partial PV tiles
  __shared__ float Rl[4][16];

  const float S = fdec(*Smax_u);
  const float ssrc = s_src[i0 + mrow];
  const float mr = lrelu(ssrc + S);   // >= every score in row mrow

  float l_acc = 0.f;
  f32x4 acc0 = {0.f,0.f,0.f,0.f}, acc1 = {0.f,0.f,0.f,0.f};
  f32x4 acc2 = {0.f,0.f,0.f,0.f}, acc3 = {0.f,0.f,0.f,0.f};

  // mask word for chunk c: mptr[c*2]; byte shift = (wv&1)*32 + quad*8
  const unsigned long long* mptr =
      mask + (size_t)(i0 + mrow) * 128 + (jbase >> 6) + (wv >> 1);
  const int sh = (wv & 1) * 32 + quad * 8;
  const float4* dptr = (const float4*)(s_dst + jbase + wv * 32 + quad * 8);
  const unsigned short* hbase =
      hTf + ((size_t)(jbase >> 5) + wv) * 2048 + (size_t)lane * 8;

  // named prefetch regs: mask group (4 chunks), s_dst depth-2 pair rotation
  unsigned long long m0 = mptr[0], m1 = mptr[2], m2 = mptr[4], m3 = mptr[6];
  float4 D0a = dptr[0],  D1a = dptr[1];
  float4 D0b = dptr[32], D1b = dptr[33];

  auto phase = [&](int c, unsigned long long mw, float4& D0, float4& D1)
      __attribute__((always_inline)) {
    const unsigned int B = (unsigned int)(mw >> sh) & 0xffu;
    float pv[8];
    {
      const float* dd = (const float*)&D0;
#pragma unroll
      for (int j = 0; j < 4; ++j) {
        const float e = lrelu(ssrc + dd[j]);
        pv[j] = (B >> j) & 1u ? __expf(e - mr) : 0.f;
      }
      dd = (const float*)&D1;
#pragma unroll
      for (int j = 0; j < 4; ++j) {
        const float e = lrelu(ssrc + dd[j]);
        pv[4 + j] = (B >> (4 + j)) & 1u ? __expf(e - mr) : 0.f;
      }
    }
    bf16x8 ps;
#pragma unroll
    for (int j = 0; j < 8; ++j) {
      l_acc += pv[j];
      ps[j] = (short)f2bf(pv[j]);
    }

    const unsigned short* hc = hbase + (size_t)c * 8192;
    const uint4 hv0 = *(const uint4*)(hc + 0 * 512);
    const uint4 hv1 = *(const uint4*)(hc + 1 * 512);
    const uint4 hv2 = *(const uint4*)(hc + 2 * 512);
    const uint4 hv3 = *(const uint4*)(hc + 3 * 512);

    if (c + 2 < kChunks) {   // depth-2 s_dst prefetch (L1/L2-hot)
      D0 = dptr[(c + 2) * 32]; D1 = dptr[(c + 2) * 32 + 1];
    }

    acc0 = __builtin_amdgcn_mfma_f32_16x16x32_bf16(ps, __builtin_bit_cast(bf16x8, hv0), acc0, 0, 0, 0);
    acc1 = __builtin_amdgcn_mfma_f32_16x16x32_bf16(ps, __builtin_bit_cast(bf16x8, hv1), acc1, 0, 0, 0);
    acc2 = __builtin_amdgcn_mfma_f32_16x16x32_bf16(ps, __builtin_bit_cast(bf16x8, hv2), acc2, 0, 0, 0);
    acc3 = __builtin_amdgcn_mfma_f32_16x16x32_bf16(ps, __builtin_bit_cast(bf16x8, hv3), acc3, 0, 0, 0);
  };

  for (int g = 0; g < 4; ++g) {
    unsigned long long n0 = 0, n1 = 0, n2 = 0, n3 = 0;
    if (g < 3) {
      n0 = mptr[g * 8 + 8]; n1 = mptr[g * 8 + 10];
      n2 = mptr[g * 8 + 12]; n3 = mptr[g * 8 + 14];
    }
    phase(g * 4 + 0, m0, D0a, D1a);
    phase(g * 4 + 1, m1, D0b, D1b);
    phase(g * 4 + 2, m2, D0a, D1a);
    phase(g * 4 + 3, m3, D0b, D1b);
    m0 = n0; m1 = n1; m2 = n2; m3 = n3;
  }

  // ---- cross-wave reduction (only barrier) ----
  float lv = l_acc;
  lv += __shfl_xor(lv, 16, 64);
  lv += __shfl_xor(lv, 32, 64);
  if (quad == 0) Rl[wv][mrow] = lv;

#pragma unroll
  for (int reg = 0; reg < 4; ++reg) {
    Racc[wv][quad * 4 + reg][0 * 16 + mrow] = acc0[reg];
    Racc[wv][quad * 4 + reg][1 * 16 + mrow] = acc1[reg];
    Racc[wv][quad * 4 + reg][2 * 16 + mrow] = acc2[reg];
    Racc[wv][quad * 4 + reg][3 * 16 + mrow] = acc3[reg];
  }
  __syncthreads();

  float* ab = accp + (size_t)b * 16 * 64;
  const int rr = t >> 4, ff = t & 15;
#pragma unroll
  for (int s = 0; s < 4; ++s) {
    const int fc = s * 16 + ff;
    ab[rr * 64 + fc] = Racc[0][rr][fc] + Racc[1][rr][fc] + Racc[2][rr][fc] + Racc[3][rr][fc];
  }
  if (t < 16) lp[(size_t)b * 16 + t] = Rl[0][t] + Rl[1][t] + Rl[2][t] + Rl[3][t];
}

// ---------------------------------------------------------------------------
// k_comb: out[i][f] = elu( (sum_q accp) / (sum_q lp) )
// ---------------------------------------------------------------------------
__global__ __launch_bounds__(256) void k_comb(const float* __restrict__ accp,
                                              const float* __restrict__ lp,
                                              float* __restrict__ out)
{
  const int gid = blockIdx.x * 256 + threadIdx.x;   // 0..524287
  const int i = gid >> 6, f = gid & 63;
  const int ib = i >> 4, il = i & 15;
  const int b0 = ib * kJSplit;
  float a = 0.f, l = 0.f;
#pragma unroll
  for (int qq = 0; qq < kJSplit; ++qq) {
    a += accp[((size_t)(b0 + qq) * 16 + il) * 64 + f];
    l += lp[(size_t)(b0 + qq) * 16 + il];
  }
  float v = a / l;
  v = v > 0.f ? v : __expf(v) - 1.f;
  out[gid] = v;
}

extern "C" void kernel_launch(void* const* d_in, const int* in_sizes, int n_in,
                              void* d_out, int out_size, void* d_ws, size_t ws_size,
                              hipStream_t stream) {
  const float* X   = (const float*)d_in[0];   // [8192][512]
  const int*   adj = (const int*)d_in[1];     // [8192][8192]
  const float* W   = (const float*)d_in[2];   // [512][64]
  const float* A   = (const float*)d_in[3];   // [128]
  float* out = (float*)d_out;                 // [8192][64] fp32

  char* ws = (char*)d_ws;
  unsigned long long* mask = (unsigned long long*)ws;  ws += (size_t)kN * 128 * 8;  // 8 MB
  unsigned short* hTf = (unsigned short*)ws;  ws += (size_t)kN * kFout * 2;         // 1 MB
  float* s_src = (float*)ws;                  ws += kN * 4;
  float* s_dst = (float*)ws;                  ws += kN * 4;
  unsigned int* Smax_u = (unsigned int*)ws;   ws += 256;
  float* accp  = (float*)ws;                  ws += (size_t)(kN / 16) * kJSplit * 16 * 64 * 4; // 8 MB
  float* lp    = (float*)ws;                  // 128 KB

  hipMemsetAsync(Smax_u, 0, 4, stream);       // capture-safe (memset node)
  k_prep <<<512 + kN / 4, 256, 0, stream>>>(adj, X, W, A, mask, hTf, s_src, s_dst, Smax_u);
  k_attn <<<(kN / 16) * kJSplit, 256, 0, stream>>>(mask, hTf, s_src, s_dst, Smax_u, accp, lp);
  k_comb <<<kN * kFout / 256, 256, 0, stream>>>(accp, lp, out);
}

// Round 8
// 427.023 us; speedup vs baseline: 1.1111x; 1.1111x over previous
//
#include <hip/hip_runtime.h>
#include <hip/hip_bf16.h>

namespace {
constexpr int kN    = 8192;
constexpr int kFin  = 512;
constexpr int kFout = 64;
constexpr float kAlpha = 0.2f;
constexpr int kJSplit = 4;                  // j-range split for k_attn
constexpr int kJLen   = kN / kJSplit;       // 2048
constexpr int kChunks = kJLen / 128;        // 16

using bf16x8 = __attribute__((ext_vector_type(8))) short;
using f32x4  = __attribute__((ext_vector_type(4))) float;

__device__ __forceinline__ unsigned short f2bf(float x) {
  return __builtin_bit_cast(unsigned short, __float2bfloat16(x));
}
__device__ __forceinline__ float lrelu(float x) {
  return fmaxf(x, kAlpha * x);   // valid since 0<alpha<1
}
// monotone float<->uint order-preserving map (for atomicMax on float)
__device__ __forceinline__ unsigned int fkey(float x) {
  unsigned int b = __float_as_uint(x);
  return (b & 0x80000000u) ? ~b : (b | 0x80000000u);
}
__device__ __forceinline__ float fdec(unsigned int k) {
  return (k & 0x80000000u) ? __uint_as_float(k ^ 0x80000000u) : __uint_as_float(~k);
}
} // namespace

// ---------------------------------------------------------------------------
// k_prep: fused (a) linear part (blocks 0..511) and (b) adj->bitmask part
// (blocks 512..2559).
//
// (b) r8 REWRITE — fill-style SWEEP: per iteration the whole mask-grid reads
//     ONE contiguous 8-MB window of adj (wave = 64 consecutive int4, lane-
//     contiguous), so DRAM row buffers see dense bursts (the r7 per-wave-row
//     crawl ran at 978 GB/s = 12% peak from row thrash). 32 iterations sweep
//     all 268 MB. Bit packing: lane nibble (4 j's) -> 64-bit OR-shuffle
//     reduce within 16-lane groups -> 4 mask words per wave per iteration.
//     Output layout identical to r7 (bit i of word w of row r = adj[r][w*64+i]).
// ---------------------------------------------------------------------------
__global__ __launch_bounds__(256) void k_prep(
    const int* __restrict__ adj, const float* __restrict__ X,
    const float* __restrict__ W, const float* __restrict__ A,
    unsigned long long* __restrict__ mask, unsigned short* __restrict__ hTf,
    float* __restrict__ s_src, float* __restrict__ s_dst,
    unsigned int* __restrict__ Smax_u)
{
  const int t = threadIdx.x;
  const int wv = t >> 6, lane = t & 63;

  if (blockIdx.x >= 512) {
    // ---------------- bitmask part: global contiguous sweep ----------------
    const int mwave = (blockIdx.x - 512) * 4 + wv;      // 0..8191
    constexpr int kMaskWaves = 2048 * 4;                // 8192
    const int4* __restrict__ a4 = (const int4*)adj;
    const int grp = lane >> 4;                           // 0..3 (word within wave span)
    const unsigned long long shft = 4ull * (lane & 15);
#pragma unroll 2
    for (int it = 0; it < 32; ++it) {
      const size_t base4 = ((size_t)it * kMaskWaves + mwave) * 64;   // int4 idx
      const int4 v = a4[base4 + lane];                   // 1 KB/wave, coalesced
      const unsigned int nib = (v.x > 0 ? 1u : 0u) | (v.y > 0 ? 2u : 0u) |
                               (v.z > 0 ? 4u : 0u) | (v.w > 0 ? 8u : 0u);
      unsigned long long val = (unsigned long long)nib << shft;
      val |= __shfl_xor(val, 1, 64);
      val |= __shfl_xor(val, 2, 64);
      val |= __shfl_xor(val, 4, 64);
      val |= __shfl_xor(val, 8, 64);                     // all 16 lanes hold word
      if ((lane & 15) == 0) {
        const size_t baseInt = base4 * 4;                // int index (row-aligned: 256 | baseInt)
        const size_t row = baseInt >> 13;                // / 8192
        const size_t jw  = (baseInt & 8191) >> 6;        // word within row
        mask[row * 128 + jw + grp] = val;
      }
    }
    return;
  }

  // ---------------- linear part (unchanged from r7 — passed) ----------------
  const int wvu = __builtin_amdgcn_readfirstlane(wv);   // provably uniform
  const int f = lane;
  const int i0 = blockIdx.x * 16;
  const int r0l = wvu * 4;

  __shared__ unsigned short h_sm[16][64];
  __shared__ float red[4];

  const float* x0 = X + (size_t)(i0 + r0l) * kFin;      // wave-uniform base
  float acc0 = 0.f, acc1 = 0.f, acc2 = 0.f, acc3 = 0.f;
#pragma unroll 2
  for (int k = 0; k < kFin; k += 4) {
    const float4 xa = *(const float4*)(x0 + k);
    const float4 xb = *(const float4*)(x0 + kFin + k);
    const float4 xc = *(const float4*)(x0 + 2 * kFin + k);
    const float4 xd = *(const float4*)(x0 + 3 * kFin + k);
#pragma unroll
    for (int j = 0; j < 4; ++j) {
      const float wk = W[(k + j) * kFout + f];          // 256B coalesced, L2
      acc0 = fmaf(((const float*)&xa)[j], wk, acc0);
      acc1 = fmaf(((const float*)&xb)[j], wk, acc1);
      acc2 = fmaf(((const float*)&xc)[j], wk, acc2);
      acc3 = fmaf(((const float*)&xd)[j], wk, acc3);
    }
  }

  // ---- scores + per-wave s_dst max ----
  const float asrc = A[f], adst = A[kFout + f];
  float accs[4] = {acc0, acc1, acc2, acc3};
  float dmax = -3.4e38f;
#pragma unroll
  for (int r = 0; r < 4; ++r) {
    float vs = accs[r] * asrc;
    float vd = accs[r] * adst;
#pragma unroll
    for (int off = 32; off > 0; off >>= 1) {
      vs += __shfl_xor(vs, off, 64);
      vd += __shfl_xor(vd, off, 64);
    }
    if (f == 0) {
      s_src[i0 + r0l + r] = vs;
      s_dst[i0 + r0l + r] = vd;
      dmax = fmaxf(dmax, vd);
    }
    h_sm[r0l + r][f] = f2bf(accs[r]);
  }
  if (f == 0) red[wvu] = dmax;
  __syncthreads();
  if (t == 0) {
    float m = fmaxf(fmaxf(red[0], red[1]), fmaxf(red[2], red[3]));
    atomicMax(Smax_u, fkey(m));
  }

  // ---- emit 2 KB hTf fragment slice, coalesced (layout proven r5/r6) ----
  if (t < 128) {
    const int jblk = i0 >> 5, half = (i0 >> 4) & 1;
    const int w = t >> 5, li = t & 31;
    const int ln = half * 32 + li;
    const int ql = li >> 4, fcol = w * 16 + (li & 15);
    bf16x8 v;
#pragma unroll
    for (int e = 0; e < 8; ++e) v[e] = (short)h_sm[ql * 8 + e][fcol];
    *(bf16x8*)(hTf + (size_t)jblk * 2048 + w * 512 + (size_t)ln * 8) = v;
  }
}

// ---------------------------------------------------------------------------
// k_attn v8: same as v7 (bitmask-driven, barrier-free) with one micro-fix:
// hv B-fragment loads hoisted ABOVE the pv/expf computation — ~120 cyc of
// free L2-latency cover per chunk.
// ---------------------------------------------------------------------------
__global__ __launch_bounds__(256) void k_attn(
    const unsigned long long* __restrict__ mask,
    const unsigned short* __restrict__ hTf,
    const float* __restrict__ s_src, const float* __restrict__ s_dst,
    const unsigned int* __restrict__ Smax_u, float* __restrict__ accp,
    float* __restrict__ lp)
{
  const int t = threadIdx.x;
  const int wv = t >> 6, lane = t & 63;
  const int b = blockIdx.x;
  const int i0 = (b >> 2) * 16;
  const int q = b & 3;
  const int jbase = q * kJLen;
  const int mrow = lane & 15, quad = lane >> 4;

  __shared__ float Racc[4][16][64];   // 16 KB: per-wave partial PV tiles
  __shared__ float Rl[4][16];

  const float S = fdec(*Smax_u);
  const float ssrc = s_src[i0 + mrow];
  const float mr = lrelu(ssrc + S);   // >= every score in row mrow

  float l_acc = 0.f;
  f32x4 acc0 = {0.f,0.f,0.f,0.f}, acc1 = {0.f,0.f,0.f,0.f};
  f32x4 acc2 = {0.f,0.f,0.f,0.f}, acc3 = {0.f,0.f,0.f,0.f};

  // mask word for chunk c: mptr[c*2]; byte shift = (wv&1)*32 + quad*8
  const unsigned long long* mptr =
      mask + (size_t)(i0 + mrow) * 128 + (jbase >> 6) + (wv >> 1);
  const int sh = (wv & 1) * 32 + quad * 8;
  const float4* dptr = (const float4*)(s_dst + jbase + wv * 32 + quad * 8);
  const unsigned short* hbase =
      hTf + ((size_t)(jbase >> 5) + wv) * 2048 + (size_t)lane * 8;

  // named prefetch regs: mask group (4 chunks), s_dst depth-2 pair rotation
  unsigned long long m0 = mptr[0], m1 = mptr[2], m2 = mptr[4], m3 = mptr[6];
  float4 D0a = dptr[0],  D1a = dptr[1];
  float4 D0b = dptr[32], D1b = dptr[33];

  auto phase = [&](int c, unsigned long long mw, float4& D0, float4& D1)
      __attribute__((always_inline)) {
    // ---- B-fragment loads FIRST: L2 latency covered by pv compute below ----
    const unsigned short* hc = hbase + (size_t)c * 8192;
    const uint4 hv0 = *(const uint4*)(hc + 0 * 512);
    const uint4 hv1 = *(const uint4*)(hc + 1 * 512);
    const uint4 hv2 = *(const uint4*)(hc + 2 * 512);
    const uint4 hv3 = *(const uint4*)(hc + 3 * 512);

    const unsigned int B = (unsigned int)(mw >> sh) & 0xffu;
    float pv[8];
    {
      const float* dd = (const float*)&D0;
#pragma unroll
      for (int j = 0; j < 4; ++j) {
        const float e = lrelu(ssrc + dd[j]);
        pv[j] = (B >> j) & 1u ? __expf(e - mr) : 0.f;
      }
      dd = (const float*)&D1;
#pragma unroll
      for (int j = 0; j < 4; ++j) {
        const float e = lrelu(ssrc + dd[j]);
        pv[4 + j] = (B >> (4 + j)) & 1u ? __expf(e - mr) : 0.f;
      }
    }
    bf16x8 ps;
#pragma unroll
    for (int j = 0; j < 8; ++j) {
      l_acc += pv[j];
      ps[j] = (short)f2bf(pv[j]);
    }

    if (c + 2 < kChunks) {   // depth-2 s_dst prefetch (L1/L2-hot)
      D0 = dptr[(c + 2) * 32]; D1 = dptr[(c + 2) * 32 + 1];
    }

    acc0 = __builtin_amdgcn_mfma_f32_16x16x32_bf16(ps, __builtin_bit_cast(bf16x8, hv0), acc0, 0, 0, 0);
    acc1 = __builtin_amdgcn_mfma_f32_16x16x32_bf16(ps, __builtin_bit_cast(bf16x8, hv1), acc1, 0, 0, 0);
    acc2 = __builtin_amdgcn_mfma_f32_16x16x32_bf16(ps, __builtin_bit_cast(bf16x8, hv2), acc2, 0, 0, 0);
    acc3 = __builtin_amdgcn_mfma_f32_16x16x32_bf16(ps, __builtin_bit_cast(bf16x8, hv3), acc3, 0, 0, 0);
  };

  for (int g = 0; g < 4; ++g) {
    unsigned long long n0 = 0, n1 = 0, n2 = 0, n3 = 0;
    if (g < 3) {
      n0 = mptr[g * 8 + 8]; n1 = mptr[g * 8 + 10];
      n2 = mptr[g * 8 + 12]; n3 = mptr[g * 8 + 14];
    }
    phase(g * 4 + 0, m0, D0a, D1a);
    phase(g * 4 + 1, m1, D0b, D1b);
    phase(g * 4 + 2, m2, D0a, D1a);
    phase(g * 4 + 3, m3, D0b, D1b);
    m0 = n0; m1 = n1; m2 = n2; m3 = n3;
  }

  // ---- cross-wave reduction (only barrier) ----
  float lv = l_acc;
  lv += __shfl_xor(lv, 16, 64);
  lv += __shfl_xor(lv, 32, 64);
  if (quad == 0) Rl[wv][mrow] = lv;

#pragma unroll
  for (int reg = 0; reg < 4; ++reg) {
    Racc[wv][quad * 4 + reg][0 * 16 + mrow] = acc0[reg];
    Racc[wv][quad * 4 + reg][1 * 16 + mrow] = acc1[reg];
    Racc[wv][quad * 4 + reg][2 * 16 + mrow] = acc2[reg];
    Racc[wv][quad * 4 + reg][3 * 16 + mrow] = acc3[reg];
  }
  __syncthreads();

  float* ab = accp + (size_t)b * 16 * 64;
  const int rr = t >> 4, ff = t & 15;
#pragma unroll
  for (int s = 0; s < 4; ++s) {
    const int fc = s * 16 + ff;
    ab[rr * 64 + fc] = Racc[0][rr][fc] + Racc[1][rr][fc] + Racc[2][rr][fc] + Racc[3][rr][fc];
  }
  if (t < 16) lp[(size_t)b * 16 + t] = Rl[0][t] + Rl[1][t] + Rl[2][t] + Rl[3][t];
}

// ---------------------------------------------------------------------------
// k_comb: out[i][f] = elu( (sum_q accp) / (sum_q lp) )
// ---------------------------------------------------------------------------
__global__ __launch_bounds__(256) void k_comb(const float* __restrict__ accp,
                                              const float* __restrict__ lp,
                                              float* __restrict__ out)
{
  const int gid = blockIdx.x * 256 + threadIdx.x;   // 0..524287
  const int i = gid >> 6, f = gid & 63;
  const int ib = i >> 4, il = i & 15;
  const int b0 = ib * kJSplit;
  float a = 0.f, l = 0.f;
#pragma unroll
  for (int qq = 0; qq < kJSplit; ++qq) {
    a += accp[((size_t)(b0 + qq) * 16 + il) * 64 + f];
    l += lp[(size_t)(b0 + qq) * 16 + il];
  }
  float v = a / l;
  v = v > 0.f ? v : __expf(v) - 1.f;
  out[gid] = v;
}

extern "C" void kernel_launch(void* const* d_in, const int* in_sizes, int n_in,
                              void* d_out, int out_size, void* d_ws, size_t ws_size,
                              hipStream_t stream) {
  const float* X   = (const float*)d_in[0];   // [8192][512]
  const int*   adj = (const int*)d_in[1];     // [8192][8192]
  const float* W   = (const float*)d_in[2];   // [512][64]
  const float* A   = (const float*)d_in[3];   // [128]
  float* out = (float*)d_out;                 // [8192][64] fp32

  char* ws = (char*)d_ws;
  unsigned long long* mask = (unsigned long long*)ws;  ws += (size_t)kN * 128 * 8;  // 8 MB
  unsigned short* hTf = (unsigned short*)ws;  ws += (size_t)kN * kFout * 2;         // 1 MB
  float* s_src = (float*)ws;                  ws += kN * 4;
  float* s_dst = (float*)ws;                  ws += kN * 4;
  unsigned int* Smax_u = (unsigned int*)ws;   ws += 256;
  float* accp  = (float*)ws;                  ws += (size_t)(kN / 16) * kJSplit * 16 * 64 * 4; // 8 MB
  float* lp    = (float*)ws;                  // 128 KB

  hipMemsetAsync(Smax_u, 0, 4, stream);       // capture-safe (memset node)
  k_prep <<<512 + 2048, 256, 0, stream>>>(adj, X, W, A, mask, hTf, s_src, s_dst, Smax_u);
  k_attn <<<(kN / 16) * kJSplit, 256, 0, stream>>>(mask, hTf, s_src, s_dst, Smax_u, accp, lp);
  k_comb <<<kN * kFout / 256, 256, 0, stream>>>(accp, lp, out);
}